// Round 10
// baseline (201.240 us; speedup 1.0000x reference)
//
#include <hip/hip_runtime.h>

// Problem constants (B=2, C=64, H=W=192, EXP=4, DG=4, K=3)
#define BN   2
#define CN   64
#define HN   192
#define WN   192
#define HWN  36864          // 192*192
#define OCN  256            // EXP*C
#define JCN  72             // DG*2*9
#define SN   32             // pixel strip for deform

// k_deform tile geometry
#define DROWS 8             // output rows per block
#define XH    17            // staged x rows
#define XW    42            // staged x cols
#define XRT   4             // row halo top
#define XCL   4             // col halo left

typedef __attribute__((ext_vector_type(8))) short bf16x8;
typedef __attribute__((ext_vector_type(4))) float f32x4;

__device__ __forceinline__ unsigned short f2bf(float f) {
    union { float f; unsigned u; } v; v.f = f;
    unsigned r = v.u + 0x7fffu + ((v.u >> 16) & 1u);
    return (unsigned short)(r >> 16);
}

// ---------------------------------------------------------------------------
// Prep:
//  job 1: w2mf = w2 (72x256) bf16, MFMA A-frag order (tm=0..4, s=0..7):
//         w2mf[((tm*8+s)*64 + l)*8 + j] = w2[tm*16+(l&15)][s*32+(l>>4)*8+j]
//  job 2: w_outmf = w_out (64x64) bf16, MFMA A-frag order (tm=0..3, s=0..1):
//         w_outmf[((tm*2+s)*64 + l)*8 + j] = w_out[tm*16+(l&15)][s*32+(l>>4)*8+j]
//  job 3: w1p[o*8+kk] = w1[o*9+k(kk)], k skips center.
// ---------------------------------------------------------------------------
__global__ __launch_bounds__(256) void k_prep(const float* __restrict__ w2,
                                              const float* __restrict__ w_out,
                                              const float* __restrict__ w1,
                                              unsigned short* __restrict__ w2mf,
                                              unsigned short* __restrict__ w_outmf,
                                              float* __restrict__ w1p) {
    int idx = blockIdx.x * 256 + threadIdx.x;
    if (idx < 20480) {
        int j  = idx & 7;
        int l  = (idx >> 3) & 63;
        int ts = idx >> 9;             // tm*8+s, 0..39
        int tm = ts >> 3, s = ts & 7;
        int jrow = tm * 16 + (l & 15);
        int k    = s * 32 + (l >> 4) * 8 + j;
        float v = (jrow < JCN) ? w2[jrow * OCN + k] : 0.f;
        w2mf[idx] = f2bf(v);
    } else if (idx < 24576) {
        int r  = idx - 20480;          // 0..4095
        int j  = r & 7;
        int l  = (r >> 3) & 63;
        int ts = r >> 9;               // tm*2+s, 0..7
        int tm = ts >> 1, s = ts & 1;
        int m  = tm * 16 + (l & 15);
        int k  = s * 32 + (l >> 4) * 8 + j;
        w_outmf[r] = f2bf(w_out[m * CN + k]);
    } else if (idx < 26624) {
        int r = idx - 24576;           // 0..2047
        int o = r >> 3, kk = r & 7;
        int k = kk < 4 ? kk : kk + 1;
        w1p[r] = w1[o * 9 + k];
    }
}

// ---------------------------------------------------------------------------
// K1: offsets t + fused x1 copy.  Fused MFMA, no LDS/barriers; prefetch
// DISTANCE 2 (loads issued ~2 chunk-iterations (~800 cyc) before use).
// ---------------------------------------------------------------------------
__global__ __launch_bounds__(256, 4) void k_offsets(const float* __restrict__ x,
                                                    const float* __restrict__ w1p,
                                                    const unsigned short* __restrict__ w2mf,
                                                    const float* __restrict__ b2,
                                                    float* __restrict__ t_out,
                                                    float* __restrict__ x_copy) {
    const int tid  = threadIdx.x;
    const int wv   = tid >> 6;
    const int lane = tid & 63;
    const int q    = lane >> 4;
    const int n    = lane & 15;
    const int n0   = blockIdx.x * 64 + wv * 16;
    const int y    = blockIdx.y;
    const int b    = blockIdx.z;
    const int xcol = n0 + n;
    const float* xb = x + (size_t)b * CN * HWN;

    auto load_chunk = [&](int s, float (*ld)[9]) {
        #pragma unroll
        for (int cc = 0; cc < 2; ++cc) {
            int c = 8 * s + 2 * q + cc;
            const float* xp = xb + (size_t)c * HWN;
            #pragma unroll
            for (int k = 0; k < 9; ++k) {
                int ky = k / 3, kx = k - 3 * ky;
                int yy = y - 1 + ky, xx = xcol - 1 + kx;
                float v = 0.f;
                if ((unsigned)yy < (unsigned)HN && (unsigned)xx < (unsigned)WN)
                    v = xp[yy * WN + xx];
                ld[cc][k] = v;
            }
        }
    };

    f32x4 acc[5];
    #pragma unroll
    for (int t = 0; t < 5; ++t) acc[t] = (f32x4){0.f, 0.f, 0.f, 0.f};

    const bf16x8* ap = (const bf16x8*)w2mf + lane;

    float lbuf[3][2][9];
    load_chunk(0, lbuf[0]);
    load_chunk(1, lbuf[1]);
    #pragma unroll
    for (int s = 0; s < 8; ++s) {
        if (s < 6) load_chunk(s + 2, lbuf[(s + 2) % 3]);
        float (*ld)[9] = lbuf[s % 3];

        float dd[2][8];
        #pragma unroll
        for (int cc = 0; cc < 2; ++cc) {
            int c = 8 * s + 2 * q + cc;
            float ctr = ld[cc][4];
            x_copy[((size_t)b * CN + c) * HWN + y * WN + xcol] = ctr;
            #pragma unroll
            for (int kk = 0; kk < 8; ++kk) {
                int k = kk < 4 ? kk : kk + 1;
                dd[cc][kk] = ld[cc][k] - ctr;
            }
        }

        // xd for this thread's 8 o's (j=0..7) -> B-fragment
        bf16x8 bfr;
        const float4* wp = (const float4*)(w1p + (size_t)(s * 32 + q * 8) * 8);
        #pragma unroll
        for (int j = 0; j < 8; ++j) {
            float4 wa = wp[2 * j];
            float4 wb = wp[2 * j + 1];
            const float* d = dd[j >> 2];
            float a = wa.x * d[0] + wa.y * d[1] + wa.z * d[2] + wa.w * d[3]
                    + wb.x * d[4] + wb.y * d[5] + wb.z * d[6] + wb.w * d[7];
            bfr[j] = (short)f2bf(a);
        }

        #pragma unroll
        for (int tm = 0; tm < 5; ++tm) {
            bf16x8 af = ap[(tm * 8 + s) * 64];
            acc[tm] = __builtin_amdgcn_mfma_f32_16x16x32_bf16(af, bfr, acc[tm], 0, 0, 0);
        }
    }

    // Epilogue (D layout: col=lane&15, row=q*4+reg)
    float* tb = t_out + (size_t)b * JCN * HWN + y * WN + n0 + n;
    #pragma unroll
    for (int tm = 0; tm < 5; ++tm) {
        #pragma unroll
        for (int r = 0; r < 4; ++r) {
            int j = tm * 16 + q * 4 + r;
            if (j < JCN)
                tb[(size_t)j * HWN] = acc[tm][r] + b2[j];
        }
    }
}

// ---------------------------------------------------------------------------
// K2: depthwise deformable conv (unchanged from round 8).
// ---------------------------------------------------------------------------
__device__ __forceinline__ float dsample(const float* __restrict__ p, int yi, int xi) {
    if ((unsigned)yi < (unsigned)HN && (unsigned)xi < (unsigned)WN)
        return p[yi * WN + xi];
    return 0.f;
}

__global__ __launch_bounds__(256, 4) void k_deform(const float* __restrict__ x,
                                                   const float* __restrict__ t_in,
                                                   const float* __restrict__ wdef,
                                                   float* __restrict__ y_out) {
    __shared__ float xs[8 * XH * XW];                 // 22848 B
    __shared__ float wks[9 * 8];                      // [k][cc]
    __shared__ float wsums[8];
    const int x0   = blockIdx.x * SN;
    const int yr0  = blockIdx.y * DROWS;
    const int zz   = blockIdx.z;
    const int b    = zz >> 3;
    const int chunk = zz & 7;                         // 8-channel chunk
    const int g    = chunk >> 1;                      // deform group
    const int tid  = threadIdx.x;
    const int r    = tid >> 5;                        // output row within tile
    const int px   = tid & 31;
    const int row_lo = yr0 - XRT;
    const int col_lo = x0 - XCL;
    const float* xb = x + (size_t)b * CN * HWN;

    // prefetch this thread's 18 offsets into registers (coalesced)
    float dyr[9], dxr[9];
    {
        const float* tbp = t_in + ((size_t)b * JCN + g * 18) * HWN
                         + (yr0 + r) * WN + x0 + px;
        #pragma unroll
        for (int k = 0; k < 9; ++k) {
            dyr[k] = tbp[(size_t)(2 * k) * HWN];
            dxr[k] = tbp[(size_t)(2 * k + 1) * HWN];
        }
    }

    // stage x window (zero-filled outside image)
    for (int idx = tid; idx < 8 * XH * XW; idx += 256) {
        int cc  = idx / (XH * XW);
        int rem = idx - cc * (XH * XW);
        int rr  = rem / XW;
        int col = rem - rr * XW;
        int yy  = row_lo + rr;
        int xx  = col_lo + col;
        float v = 0.f;
        if ((unsigned)yy < (unsigned)HN && (unsigned)xx < (unsigned)WN)
            v = xb[(size_t)(chunk * 8 + cc) * HWN + yy * WN + xx];
        xs[idx] = v;
    }
    // stage weights
    if (tid < 72) {
        int k = tid >> 3, cc = tid & 7;
        wks[tid] = wdef[(chunk * 8 + cc) * 9 + k];
    } else if (tid < 80) {
        int cc = tid - 72;
        float s = 0.f;
        #pragma unroll
        for (int k = 0; k < 9; ++k) s += wdef[(chunk * 8 + cc) * 9 + k];
        wsums[cc] = s;
    }
    __syncthreads();

    float acc[8];
    #pragma unroll
    for (int c = 0; c < 8; ++c)
        acc[c] = -xs[c * (XH * XW) + (XRT + r) * XW + XCL + px] * wsums[c];

    const float ry_basef = (float)(yr0 + r - 1);
    const float rx_basef = (float)(x0 + px - 1);

    #pragma unroll
    for (int k = 0; k < 9; ++k) {
        const int ky = k / 3, kx = k - 3 * ky;
        float py  = ry_basef + (float)ky + dyr[k];
        float pxf = rx_basef + (float)kx + dxr[k];
        float y0f = floorf(py), x0f = floorf(pxf);
        float wy = py - y0f, wx = pxf - x0f;
        int yi = (int)y0f, xi = (int)x0f;
        int ry = yi - row_lo, rx = xi - col_lo;
        float omwy = 1.f - wy, omwx = 1.f - wx;
        float w00 = omwy * omwx;
        float w01 = omwy * wx;
        float w10 = wy * omwx;
        float w11 = wy * wx;
        float4 wka = *(const float4*)&wks[k * 8];
        float4 wkb = *(const float4*)&wks[k * 8 + 4];
        float wkv[8] = {wka.x, wka.y, wka.z, wka.w, wkb.x, wkb.y, wkb.z, wkb.w};
        if ((unsigned)ry < (XH - 1) && (unsigned)rx < (XW - 1)) {
            const float* p0 = xs + ry * XW + rx;
            #pragma unroll
            for (int c = 0; c < 8; ++c) {
                const float* p = p0 + c * (XH * XW);
                float bil = p[0] * w00 + p[1] * w01 + p[XW] * w10 + p[XW + 1] * w11;
                acc[c] += wkv[c] * bil;
            }
        } else {
            #pragma unroll
            for (int c = 0; c < 8; ++c) {
                const float* xp = xb + (size_t)(chunk * 8 + c) * HWN;
                float v00 = dsample(xp, yi,     xi);
                float v01 = dsample(xp, yi,     xi + 1);
                float v10 = dsample(xp, yi + 1, xi);
                float v11 = dsample(xp, yi + 1, xi + 1);
                float bil = v00 * w00 + v01 * w01 + v10 * w10 + v11 * w11;
                acc[c] += wkv[c] * bil;
            }
        }
    }

    float* yo = y_out + ((size_t)b * CN + chunk * 8) * HWN + (yr0 + r) * WN + x0 + px;
    #pragma unroll
    for (int c = 0; c < 8; ++c)
        yo[(size_t)c * HWN] = acc[c];
}

// ---------------------------------------------------------------------------
// K3: m = w_out . y via MFMA.  Thread l loads its B-frag elements of y
// straight from global (no LDS, no barrier); A = pre-packed bf16 w_outmf.
// ---------------------------------------------------------------------------
__global__ __launch_bounds__(256, 8) void k_final(const float* __restrict__ y_in,
                                                  const unsigned short* __restrict__ womf,
                                                  float* __restrict__ m_out) {
    const int tid  = threadIdx.x;
    const int wv   = tid >> 6;
    const int lane = tid & 63;
    const int q    = lane >> 4;
    const int n    = lane & 15;
    const int n0   = blockIdx.x * 64 + wv * 16;
    const int yr   = blockIdx.y;
    const int b    = blockIdx.z;

    const float* yb = y_in + (size_t)b * CN * HWN + yr * WN + n0 + n;

    float yv[2][8];
    #pragma unroll
    for (int s = 0; s < 2; ++s)
        #pragma unroll
        for (int j = 0; j < 8; ++j)
            yv[s][j] = yb[(size_t)(s * 32 + q * 8 + j) * HWN];

    bf16x8 bfr[2];
    #pragma unroll
    for (int s = 0; s < 2; ++s)
        #pragma unroll
        for (int j = 0; j < 8; ++j)
            bfr[s][j] = (short)f2bf(yv[s][j]);

    const bf16x8* ap = (const bf16x8*)womf + lane;
    f32x4 acc[4];
    #pragma unroll
    for (int tm = 0; tm < 4; ++tm) acc[tm] = (f32x4){0.f, 0.f, 0.f, 0.f};
    #pragma unroll
    for (int tm = 0; tm < 4; ++tm) {
        #pragma unroll
        for (int s = 0; s < 2; ++s) {
            bf16x8 af = ap[(tm * 2 + s) * 64];
            acc[tm] = __builtin_amdgcn_mfma_f32_16x16x32_bf16(af, bfr[s], acc[tm], 0, 0, 0);
        }
    }

    // D layout: col=lane&15, row=q*4+reg ; o = tm*16 + q*4 + r
    float* mb = m_out + (size_t)b * CN * HWN + yr * WN + n0 + n;
    #pragma unroll
    for (int tm = 0; tm < 4; ++tm) {
        #pragma unroll
        for (int r = 0; r < 4; ++r)
            mb[(size_t)(tm * 16 + q * 4 + r) * HWN] = acc[tm][r];
    }
}

// ---------------------------------------------------------------------------
extern "C" void kernel_launch(void* const* d_in, const int* in_sizes, int n_in,
                              void* d_out, int out_size, void* d_ws, size_t ws_size,
                              hipStream_t stream) {
    const float* x1    = (const float*)d_in[0];   // 2*64*192*192
    const float* w_off1 = (const float*)d_in[1];  // 256*9
    const float* w_off2 = (const float*)d_in[2];  // 72*256
    const float* b_off2 = (const float*)d_in[3];  // 72
    const float* w_def = (const float*)d_in[4];   // 64*9
    const float* w_out = (const float*)d_in[5];   // 64*64

    float* out = (float*)d_out;
    const size_t n_x = (size_t)BN * CN * HWN;     // 4718592
    float* out_x1 = out;                          // output 0: x1 copy (fused into k_offsets)
    float* out_m  = out + n_x;                    // output 1: m

    // Workspace layout (bytes)
    char* ws0 = (char*)d_ws;
    unsigned short* w2mf   = (unsigned short*)ws0;          // 20480 bf16 = 40960 B
    unsigned short* w_outmf = (unsigned short*)(ws0 + 40960); // 4096 bf16 = 8192 B
    float* w1p    = (float*)(ws0 + 49152);                  // 2048 f = 8192 B
    float* t_ws   = (float*)(ws0 + 57344);                  // 2*72*36864 f
    float* y_ws   = t_ws + (size_t)BN * JCN * HWN;          // 2*64*36864 f

    dim3 blk(256);

    k_prep<<<dim3(104), blk, 0, stream>>>(w_off2, w_out, w_off1, w2mf, w_outmf, w1p);
    k_offsets<<<dim3(WN / 64, HN, BN), blk, 0, stream>>>(x1, w1p, w2mf, b_off2,
                                                         t_ws, out_x1);
    k_deform<<<dim3(WN / SN, HN / DROWS, BN * 8), blk, 0, stream>>>(x1, t_ws, w_def, y_ws);
    k_final<<<dim3(WN / 64, HN, BN), blk, 0, stream>>>(y_ws, w_outmf, out_m);
}

// Round 11
// 182.136 us; speedup vs baseline: 1.1049x; 1.1049x over previous
//
#include <hip/hip_runtime.h>

// Problem constants (B=2, C=64, H=W=192, EXP=4, DG=4, K=3)
#define BN   2
#define CN   64
#define HN   192
#define WN   192
#define HWN  36864          // 192*192
#define OCN  256            // EXP*C
#define JCN  72             // DG*2*9
#define SN   32             // pixel strip for deform

// k_deform tile geometry
#define DROWS 8             // output rows per block
#define XH    17            // staged x rows
#define XW    42            // staged x cols
#define XRT   4             // row halo top
#define XCL   4             // col halo left

typedef __attribute__((ext_vector_type(8))) short bf16x8;
typedef __attribute__((ext_vector_type(4))) float f32x4;

__device__ __forceinline__ unsigned short f2bf(float f) {
    union { float f; unsigned u; } v; v.f = f;
    unsigned r = v.u + 0x7fffu + ((v.u >> 16) & 1u);
    return (unsigned short)(r >> 16);
}

// ---------------------------------------------------------------------------
// Prep:
//  job 1: w2mf = w2 (72x256) bf16, MFMA A-frag order (tm=0..4, s=0..7)
//  job 2: w_outmf = w_out (64x64) bf16, MFMA A-frag order (tm=0..3, s=0..1)
//  job 3: w1p[o*8+kk] = w1[o*9+k(kk)], k skips center.
// ---------------------------------------------------------------------------
__global__ __launch_bounds__(256) void k_prep(const float* __restrict__ w2,
                                              const float* __restrict__ w_out,
                                              const float* __restrict__ w1,
                                              unsigned short* __restrict__ w2mf,
                                              unsigned short* __restrict__ w_outmf,
                                              float* __restrict__ w1p) {
    int idx = blockIdx.x * 256 + threadIdx.x;
    if (idx < 20480) {
        int j  = idx & 7;
        int l  = (idx >> 3) & 63;
        int ts = idx >> 9;             // tm*8+s, 0..39
        int tm = ts >> 3, s = ts & 7;
        int jrow = tm * 16 + (l & 15);
        int k    = s * 32 + (l >> 4) * 8 + j;
        float v = (jrow < JCN) ? w2[jrow * OCN + k] : 0.f;
        w2mf[idx] = f2bf(v);
    } else if (idx < 24576) {
        int r  = idx - 20480;          // 0..4095
        int j  = r & 7;
        int l  = (r >> 3) & 63;
        int ts = r >> 9;               // tm*2+s, 0..7
        int tm = ts >> 1, s = ts & 1;
        int m  = tm * 16 + (l & 15);
        int k  = s * 32 + (l >> 4) * 8 + j;
        w_outmf[r] = f2bf(w_out[m * CN + k]);
    } else if (idx < 26624) {
        int r = idx - 24576;           // 0..2047
        int o = r >> 3, kk = r & 7;
        int k = kk < 4 ? kk : kk + 1;
        w1p[r] = w1[o * 9 + k];
    }
}

// ---------------------------------------------------------------------------
// K1: offsets t + fused x1 copy.  Fused MFMA, no LDS/barriers, prefetch
// distance 1.  NOTE: distance-2 (lbuf[3]) spills at the ~64-VGPR budget the
// compiler targets under (256,4) — +24 MB scratch WRITE_SIZE, 53->72 us
// (round 10).  Keep lbuf[2].
// ---------------------------------------------------------------------------
__global__ __launch_bounds__(256, 4) void k_offsets(const float* __restrict__ x,
                                                    const float* __restrict__ w1p,
                                                    const unsigned short* __restrict__ w2mf,
                                                    const float* __restrict__ b2,
                                                    float* __restrict__ t_out,
                                                    float* __restrict__ x_copy) {
    const int tid  = threadIdx.x;
    const int wv   = tid >> 6;
    const int lane = tid & 63;
    const int q    = lane >> 4;
    const int n    = lane & 15;
    const int n0   = blockIdx.x * 64 + wv * 16;
    const int y    = blockIdx.y;
    const int b    = blockIdx.z;
    const int xcol = n0 + n;
    const float* xb = x + (size_t)b * CN * HWN;

    auto load_chunk = [&](int s, float (*ld)[9]) {
        #pragma unroll
        for (int cc = 0; cc < 2; ++cc) {
            int c = 8 * s + 2 * q + cc;
            const float* xp = xb + (size_t)c * HWN;
            #pragma unroll
            for (int k = 0; k < 9; ++k) {
                int ky = k / 3, kx = k - 3 * ky;
                int yy = y - 1 + ky, xx = xcol - 1 + kx;
                float v = 0.f;
                if ((unsigned)yy < (unsigned)HN && (unsigned)xx < (unsigned)WN)
                    v = xp[yy * WN + xx];
                ld[cc][k] = v;
            }
        }
    };

    f32x4 acc[5];
    #pragma unroll
    for (int t = 0; t < 5; ++t) acc[t] = (f32x4){0.f, 0.f, 0.f, 0.f};

    const bf16x8* ap = (const bf16x8*)w2mf + lane;

    float lbuf[2][2][9];
    load_chunk(0, lbuf[0]);
    #pragma unroll
    for (int s = 0; s < 8; ++s) {
        if (s < 7) load_chunk(s + 1, lbuf[(s + 1) & 1]);
        float (*ld)[9] = lbuf[s & 1];

        float dd[2][8];
        #pragma unroll
        for (int cc = 0; cc < 2; ++cc) {
            int c = 8 * s + 2 * q + cc;
            float ctr = ld[cc][4];
            x_copy[((size_t)b * CN + c) * HWN + y * WN + xcol] = ctr;
            #pragma unroll
            for (int kk = 0; kk < 8; ++kk) {
                int k = kk < 4 ? kk : kk + 1;
                dd[cc][kk] = ld[cc][k] - ctr;
            }
        }

        // xd for this thread's 8 o's (j=0..7) -> B-fragment
        bf16x8 bfr;
        const float4* wp = (const float4*)(w1p + (size_t)(s * 32 + q * 8) * 8);
        #pragma unroll
        for (int j = 0; j < 8; ++j) {
            float4 wa = wp[2 * j];
            float4 wb = wp[2 * j + 1];
            const float* d = dd[j >> 2];
            float a = wa.x * d[0] + wa.y * d[1] + wa.z * d[2] + wa.w * d[3]
                    + wb.x * d[4] + wb.y * d[5] + wb.z * d[6] + wb.w * d[7];
            bfr[j] = (short)f2bf(a);
        }

        #pragma unroll
        for (int tm = 0; tm < 5; ++tm) {
            bf16x8 af = ap[(tm * 8 + s) * 64];
            acc[tm] = __builtin_amdgcn_mfma_f32_16x16x32_bf16(af, bfr, acc[tm], 0, 0, 0);
        }
    }

    // Epilogue (D layout: col=lane&15, row=q*4+reg)
    float* tb = t_out + (size_t)b * JCN * HWN + y * WN + n0 + n;
    #pragma unroll
    for (int tm = 0; tm < 5; ++tm) {
        #pragma unroll
        for (int r = 0; r < 4; ++r) {
            int j = tm * 16 + q * 4 + r;
            if (j < JCN)
                tb[(size_t)j * HWN] = acc[tm][r] + b2[j];
        }
    }
}

// ---------------------------------------------------------------------------
// K2: depthwise deformable conv (unchanged).
// ---------------------------------------------------------------------------
__device__ __forceinline__ float dsample(const float* __restrict__ p, int yi, int xi) {
    if ((unsigned)yi < (unsigned)HN && (unsigned)xi < (unsigned)WN)
        return p[yi * WN + xi];
    return 0.f;
}

__global__ __launch_bounds__(256, 4) void k_deform(const float* __restrict__ x,
                                                   const float* __restrict__ t_in,
                                                   const float* __restrict__ wdef,
                                                   float* __restrict__ y_out) {
    __shared__ float xs[8 * XH * XW];                 // 22848 B
    __shared__ float wks[9 * 8];                      // [k][cc]
    __shared__ float wsums[8];
    const int x0   = blockIdx.x * SN;
    const int yr0  = blockIdx.y * DROWS;
    const int zz   = blockIdx.z;
    const int b    = zz >> 3;
    const int chunk = zz & 7;                         // 8-channel chunk
    const int g    = chunk >> 1;                      // deform group
    const int tid  = threadIdx.x;
    const int r    = tid >> 5;                        // output row within tile
    const int px   = tid & 31;
    const int row_lo = yr0 - XRT;
    const int col_lo = x0 - XCL;
    const float* xb = x + (size_t)b * CN * HWN;

    // prefetch this thread's 18 offsets into registers (coalesced)
    float dyr[9], dxr[9];
    {
        const float* tbp = t_in + ((size_t)b * JCN + g * 18) * HWN
                         + (yr0 + r) * WN + x0 + px;
        #pragma unroll
        for (int k = 0; k < 9; ++k) {
            dyr[k] = tbp[(size_t)(2 * k) * HWN];
            dxr[k] = tbp[(size_t)(2 * k + 1) * HWN];
        }
    }

    // stage x window (zero-filled outside image)
    for (int idx = tid; idx < 8 * XH * XW; idx += 256) {
        int cc  = idx / (XH * XW);
        int rem = idx - cc * (XH * XW);
        int rr  = rem / XW;
        int col = rem - rr * XW;
        int yy  = row_lo + rr;
        int xx  = col_lo + col;
        float v = 0.f;
        if ((unsigned)yy < (unsigned)HN && (unsigned)xx < (unsigned)WN)
            v = xb[(size_t)(chunk * 8 + cc) * HWN + yy * WN + xx];
        xs[idx] = v;
    }
    // stage weights
    if (tid < 72) {
        int k = tid >> 3, cc = tid & 7;
        wks[tid] = wdef[(chunk * 8 + cc) * 9 + k];
    } else if (tid < 80) {
        int cc = tid - 72;
        float s = 0.f;
        #pragma unroll
        for (int k = 0; k < 9; ++k) s += wdef[(chunk * 8 + cc) * 9 + k];
        wsums[cc] = s;
    }
    __syncthreads();

    float acc[8];
    #pragma unroll
    for (int c = 0; c < 8; ++c)
        acc[c] = -xs[c * (XH * XW) + (XRT + r) * XW + XCL + px] * wsums[c];

    const float ry_basef = (float)(yr0 + r - 1);
    const float rx_basef = (float)(x0 + px - 1);

    #pragma unroll
    for (int k = 0; k < 9; ++k) {
        const int ky = k / 3, kx = k - 3 * ky;
        float py  = ry_basef + (float)ky + dyr[k];
        float pxf = rx_basef + (float)kx + dxr[k];
        float y0f = floorf(py), x0f = floorf(pxf);
        float wy = py - y0f, wx = pxf - x0f;
        int yi = (int)y0f, xi = (int)x0f;
        int ry = yi - row_lo, rx = xi - col_lo;
        float omwy = 1.f - wy, omwx = 1.f - wx;
        float w00 = omwy * omwx;
        float w01 = omwy * wx;
        float w10 = wy * omwx;
        float w11 = wy * wx;
        float4 wka = *(const float4*)&wks[k * 8];
        float4 wkb = *(const float4*)&wks[k * 8 + 4];
        float wkv[8] = {wka.x, wka.y, wka.z, wka.w, wkb.x, wkb.y, wkb.z, wkb.w};
        if ((unsigned)ry < (XH - 1) && (unsigned)rx < (XW - 1)) {
            const float* p0 = xs + ry * XW + rx;
            #pragma unroll
            for (int c = 0; c < 8; ++c) {
                const float* p = p0 + c * (XH * XW);
                float bil = p[0] * w00 + p[1] * w01 + p[XW] * w10 + p[XW + 1] * w11;
                acc[c] += wkv[c] * bil;
            }
        } else {
            #pragma unroll
            for (int c = 0; c < 8; ++c) {
                const float* xp = xb + (size_t)(chunk * 8 + c) * HWN;
                float v00 = dsample(xp, yi,     xi);
                float v01 = dsample(xp, yi,     xi + 1);
                float v10 = dsample(xp, yi + 1, xi);
                float v11 = dsample(xp, yi + 1, xi + 1);
                float bil = v00 * w00 + v01 * w01 + v10 * w10 + v11 * w11;
                acc[c] += wkv[c] * bil;
            }
        }
    }

    float* yo = y_out + ((size_t)b * CN + chunk * 8) * HWN + (yr0 + r) * WN + x0 + px;
    #pragma unroll
    for (int c = 0; c < 8; ++c)
        yo[(size_t)c * HWN] = acc[c];
}

// ---------------------------------------------------------------------------
// K3: m = w_out . y via MFMA (no LDS, no barrier).
// ---------------------------------------------------------------------------
__global__ __launch_bounds__(256, 8) void k_final(const float* __restrict__ y_in,
                                                  const unsigned short* __restrict__ womf,
                                                  float* __restrict__ m_out) {
    const int tid  = threadIdx.x;
    const int wv   = tid >> 6;
    const int lane = tid & 63;
    const int q    = lane >> 4;
    const int n    = lane & 15;
    const int n0   = blockIdx.x * 64 + wv * 16;
    const int yr   = blockIdx.y;
    const int b    = blockIdx.z;

    const float* yb = y_in + (size_t)b * CN * HWN + yr * WN + n0 + n;

    float yv[2][8];
    #pragma unroll
    for (int s = 0; s < 2; ++s)
        #pragma unroll
        for (int j = 0; j < 8; ++j)
            yv[s][j] = yb[(size_t)(s * 32 + q * 8 + j) * HWN];

    bf16x8 bfr[2];
    #pragma unroll
    for (int s = 0; s < 2; ++s)
        #pragma unroll
        for (int j = 0; j < 8; ++j)
            bfr[s][j] = (short)f2bf(yv[s][j]);

    const bf16x8* ap = (const bf16x8*)womf + lane;
    f32x4 acc[4];
    #pragma unroll
    for (int tm = 0; tm < 4; ++tm) acc[tm] = (f32x4){0.f, 0.f, 0.f, 0.f};
    #pragma unroll
    for (int tm = 0; tm < 4; ++tm) {
        #pragma unroll
        for (int s = 0; s < 2; ++s) {
            bf16x8 af = ap[(tm * 2 + s) * 64];
            acc[tm] = __builtin_amdgcn_mfma_f32_16x16x32_bf16(af, bfr[s], acc[tm], 0, 0, 0);
        }
    }

    // D layout: col=lane&15, row=q*4+reg ; o = tm*16 + q*4 + r
    float* mb = m_out + (size_t)b * CN * HWN + yr * WN + n0 + n;
    #pragma unroll
    for (int tm = 0; tm < 4; ++tm) {
        #pragma unroll
        for (int r = 0; r < 4; ++r)
            mb[(size_t)(tm * 16 + q * 4 + r) * HWN] = acc[tm][r];
    }
}

// ---------------------------------------------------------------------------
extern "C" void kernel_launch(void* const* d_in, const int* in_sizes, int n_in,
                              void* d_out, int out_size, void* d_ws, size_t ws_size,
                              hipStream_t stream) {
    const float* x1    = (const float*)d_in[0];   // 2*64*192*192
    const float* w_off1 = (const float*)d_in[1];  // 256*9
    const float* w_off2 = (const float*)d_in[2];  // 72*256
    const float* b_off2 = (const float*)d_in[3];  // 72
    const float* w_def = (const float*)d_in[4];   // 64*9
    const float* w_out = (const float*)d_in[5];   // 64*64

    float* out = (float*)d_out;
    const size_t n_x = (size_t)BN * CN * HWN;     // 4718592
    float* out_x1 = out;                          // output 0: x1 copy (fused into k_offsets)
    float* out_m  = out + n_x;                    // output 1: m

    // Workspace layout (bytes)
    char* ws0 = (char*)d_ws;
    unsigned short* w2mf   = (unsigned short*)ws0;          // 20480 bf16 = 40960 B
    unsigned short* w_outmf = (unsigned short*)(ws0 + 40960); // 4096 bf16 = 8192 B
    float* w1p    = (float*)(ws0 + 49152);                  // 2048 f = 8192 B
    float* t_ws   = (float*)(ws0 + 57344);                  // 2*72*36864 f
    float* y_ws   = t_ws + (size_t)BN * JCN * HWN;          // 2*64*36864 f

    dim3 blk(256);

    k_prep<<<dim3(104), blk, 0, stream>>>(w_off2, w_out, w_off1, w2mf, w_outmf, w1p);
    k_offsets<<<dim3(WN / 64, HN, BN), blk, 0, stream>>>(x1, w1p, w2mf, b_off2,
                                                         t_ws, out_x1);
    k_deform<<<dim3(WN / SN, HN / DROWS, BN * 8), blk, 0, stream>>>(x1, t_ws, w_def, y_ws);
    k_final<<<dim3(WN / 64, HN, BN), blk, 0, stream>>>(y_ws, w_outmf, out_m);
}